// Round 3
// baseline (372.036 us; speedup 1.0000x reference)
//
#include <hip/hip_runtime.h>

typedef unsigned short u16;
typedef unsigned int   u32;

#define BATCH 4
#define SEQ   8192
#define DIM   1024
#define FL    2048
#define TROW  10240   // padded time row: max read = t0max+kkmax+31 = 10239

// main kernel tiling
#define BM 512        // time rows per block
#define BN 64         // dims per block
#define WOFF 64       // W[w][j] = filt[w - WOFF + j]
#define NW   2272     // windows: read range [2, 2262]
#define NHALF 68      // active 32-k halves per wave (exact band: 17*4)

typedef float  f32x4  __attribute__((ext_vector_type(4)));
typedef __bf16 bf16x8 __attribute__((ext_vector_type(8)));
typedef short  s16x8  __attribute__((ext_vector_type(8)));

__device__ __forceinline__ u16 f2bf(float f) {
  u32 u = __float_as_uint(f);
  u += 0x7fffu + ((u >> 16) & 1u);   // round-to-nearest-even
  return (u16)(u >> 16);
}

// ---- pass 1: x[b][t][d] fp32 -> xT[b][d][t] bf16, zero-padded for t in [SEQ, TROW)
__global__ __launch_bounds__(256) void k_transpose(const float* __restrict__ x,
                                                   u16* __restrict__ xT) {
  __shared__ __align__(16) u16 sm[64 * 66];   // [t][d], stride 66 breaks bank conflicts
  const int bid = blockIdx.x;
  const int tb = bid % (TROW / 64);
  const int db = (bid / (TROW / 64)) % (DIM / 64);
  const int b  = bid / ((TROW / 64) * (DIM / 64));
  const int t0 = tb * 64, d0 = db * 64;
  const int tid = threadIdx.x;

  const int c4 = tid & 15;
  const int lt = tid >> 4;
  const float* xb = x + (size_t)b * SEQ * DIM + d0 + c4 * 4;
  #pragma unroll
  for (int s = 0; s < 64; s += 16) {
    const int tl = lt + s;
    const int t = t0 + tl;
    float4 v = make_float4(0.f, 0.f, 0.f, 0.f);
    if (t < SEQ) v = *(const float4*)(xb + (size_t)t * DIM);
    u32 p0 = (u32)f2bf(v.x) | ((u32)f2bf(v.y) << 16);
    u32 p1 = (u32)f2bf(v.z) | ((u32)f2bf(v.w) << 16);
    u32* dst = (u32*)&sm[tl * 66 + c4 * 4];
    dst[0] = p0;
    dst[1] = p1;
  }
  __syncthreads();
  // store: lane packs 8 consecutive t (16 B) per d row -> dwordx4 stores
  const int q  = tid & 7;
  const int dl = tid >> 3;   // 0..31
  u16* xo = xT + ((size_t)b * DIM + d0) * TROW + t0 + 8 * q;
  #pragma unroll
  for (int s = 0; s < 2; ++s) {
    const int d = dl + 32 * s;
    u32 w[4];
    #pragma unroll
    for (int h = 0; h < 4; ++h) {
      w[h] = (u32)sm[(8 * q + 2 * h) * 66 + d] |
             ((u32)sm[(8 * q + 2 * h + 1) * 66 + d] << 16);
    }
    *(uint4*)(xo + (size_t)d * TROW) = *(const uint4*)w;
  }
}

// ---- pass 2: banded-Toeplitz MFMA conv, barrier-free K-loop.
// Out[t,d] = sum_k filt[k-t] * x[k,d].  A = Toeplitz (t), B = xT (d), K = k.
// Wave: 128(t) x 64(d) = 8 m-tiles x 4 n-tiles of 16x16x32 MFMA.
// B-fragments load DIRECTLY global->VGPR (16 B/lane, k-contiguous): no LDS
// staging, no K-loop barriers -> compiler pipelines vmcnt loads ahead freely.
// A shift-register statically renamed via 4-half unroll (no v_mov rolls):
//   m-tile 2j   uses A0 loaded j halves ago (window w0 - 32j)
//   m-tile 2j+1 uses A1 loaded j halves ago (window w0 - 16 - 32j)
__global__ __launch_bounds__(256, 2) void k_conv(const u16* __restrict__ xT,
                                                 const float* __restrict__ filt,
                                                 float* __restrict__ out) {
  __shared__ __align__(16) u16 Wb[NW * 8];    // filter windows, 35.5 KB

  const int bid = blockIdx.x;
  const int tb = bid & 15;
  const int db = (bid >> 4) & 15;
  const int b  = bid >> 8;
  const int t0 = tb * BM;
  const int d0 = db * BN;

  const int tid  = threadIdx.x;
  const int wid  = tid >> 6;
  const int lane = tid & 63;
  const int quad = lane >> 4;
  const int lq   = lane & 15;
  const int Tw   = wid * 128;   // wave's time base within block

  // build filter windows: Wb[w][j] = bf16(filt[w - WOFF + j]), zeros outside [0,FL)
  for (int w = tid; w < NW; w += 256) {
    const int base = w - WOFF;
    u32 pk[4];
    #pragma unroll
    for (int h = 0; h < 4; ++h) {
      const int i0 = base + 2 * h;
      const int i1 = i0 + 1;
      const float v0 = (i0 >= 0 && i0 < FL) ? filt[i0] : 0.f;
      const float v1 = (i1 >= 0 && i1 < FL) ? filt[i1] : 0.f;
      pk[h] = (u32)f2bf(v0) | ((u32)f2bf(v1) << 16);
    }
    u32* dst = (u32*)&Wb[w * 8];
    dst[0] = pk[0]; dst[1] = pk[1]; dst[2] = pk[2]; dst[3] = pk[3];
  }
  __syncthreads();   // the only barrier

  // B global pointers: lane reads row (d0 + nt*16 + lq), k-offset quad*8 + kk.
  // All 16 B aligned (TROW*2 and t0*2 are multiples of 16).
  const u16* xrow = xT + ((size_t)b * DIM + d0) * TROW + t0 + quad * 8;
  const u16* gB0 = xrow + (size_t)(0 * 16 + lq) * TROW;
  const u16* gB1 = xrow + (size_t)(1 * 16 + lq) * TROW;
  const u16* gB2 = xrow + (size_t)(2 * 16 + lq) * TROW;
  const u16* gB3 = xrow + (size_t)(3 * 16 + lq) * TROW;

  f32x4 acc[8][4];
  const f32x4 fz = {0.f, 0.f, 0.f, 0.f};
  #pragma unroll
  for (int i = 0; i < 8; ++i)
    #pragma unroll
    for (int j = 0; j < 4; ++j) acc[i][j] = fz;

  const s16x8 sz = {0, 0, 0, 0, 0, 0, 0, 0};
  bf16x8 A0[4], A1[4];
  A0[1] = A0[2] = A0[3] = __builtin_bit_cast(bf16x8, sz);
  A1[1] = A1[2] = A1[3] = A0[1];
  A0[0] = A0[1]; A1[0] = A1[1];

  // active halves: kk = (4*wid + i)*32, i in [0, 68).  (kk >= Tw-31 && kk <= Tw+2174)
  const int wconst = quad * 8 - Tw - lq + WOFF;
  const int kkBase = 4 * wid * 32;

  for (int g = 0; g < NHALF / 4; ++g) {
    #pragma unroll
    for (int r = 0; r < 4; ++r) {
      const int kk = kkBase + (g * 4 + r) * 32;
      bf16x8 bfr[4];
      bfr[0] = *(const bf16x8*)(gB0 + kk);
      bfr[1] = *(const bf16x8*)(gB1 + kk);
      bfr[2] = *(const bf16x8*)(gB2 + kk);
      bfr[3] = *(const bf16x8*)(gB3 + kk);
      const int w0 = kk + wconst;
      A0[r] = *(const bf16x8*)&Wb[w0 * 8];
      A1[r] = *(const bf16x8*)&Wb[(w0 - 16) * 8];
      #pragma unroll
      for (int nt = 0; nt < 4; ++nt) {
        acc[0][nt] = __builtin_amdgcn_mfma_f32_16x16x32_bf16(A0[r],           bfr[nt], acc[0][nt], 0, 0, 0);
        acc[1][nt] = __builtin_amdgcn_mfma_f32_16x16x32_bf16(A1[r],           bfr[nt], acc[1][nt], 0, 0, 0);
        acc[2][nt] = __builtin_amdgcn_mfma_f32_16x16x32_bf16(A0[(r + 3) & 3], bfr[nt], acc[2][nt], 0, 0, 0);
        acc[3][nt] = __builtin_amdgcn_mfma_f32_16x16x32_bf16(A1[(r + 3) & 3], bfr[nt], acc[3][nt], 0, 0, 0);
        acc[4][nt] = __builtin_amdgcn_mfma_f32_16x16x32_bf16(A0[(r + 2) & 3], bfr[nt], acc[4][nt], 0, 0, 0);
        acc[5][nt] = __builtin_amdgcn_mfma_f32_16x16x32_bf16(A1[(r + 2) & 3], bfr[nt], acc[5][nt], 0, 0, 0);
        acc[6][nt] = __builtin_amdgcn_mfma_f32_16x16x32_bf16(A0[(r + 1) & 3], bfr[nt], acc[6][nt], 0, 0, 0);
        acc[7][nt] = __builtin_amdgcn_mfma_f32_16x16x32_bf16(A1[(r + 1) & 3], bfr[nt], acc[7][nt], 0, 0, 0);
      }
    }
  }

  // epilogue: C/D layout col = lane&15 (d), row = quad*4 + reg (t)
  float* ob = out + ((size_t)b * SEQ + t0 + Tw) * DIM + d0;
  #pragma unroll
  for (int mt = 0; mt < 8; ++mt) {
    #pragma unroll
    for (int nt = 0; nt < 4; ++nt) {
      #pragma unroll
      for (int r = 0; r < 4; ++r) {
        ob[(size_t)(mt * 16 + quad * 4 + r) * DIM + nt * 16 + lq] = acc[mt][nt][r];
      }
    }
  }
}

extern "C" void kernel_launch(void* const* d_in, const int* in_sizes, int n_in,
                              void* d_out, int out_size, void* d_ws, size_t ws_size,
                              hipStream_t stream) {
  const float* x    = (const float*)d_in[0];
  const float* filt = (const float*)d_in[1];
  float* out = (float*)d_out;
  u16* xT = (u16*)d_ws;   // needs 4*1024*10240*2 = 83.9 MB of workspace
  (void)in_sizes; (void)n_in; (void)out_size; (void)ws_size;

  k_transpose<<<BATCH * (TROW / 64) * (DIM / 64), 256, 0, stream>>>(x, xT);
  k_conv<<<BATCH * 16 * 16, 256, 0, stream>>>(xT, filt, out);
}